// Round 7
// baseline (387.742 us; speedup 1.0000x reference)
//
#include <hip/hip_runtime.h>
#include <math.h>

#define IMG_W   800
#define IMG_PIX (IMG_W * IMG_W)
#define NEDGE   6000
#define NSRC    4
#define NVIEW   5
// d_out layout (floats):
//   sim loss : [0, NSRC*NEDGE)
//   mask     : [NSRC*NEDGE, 2*NSRC*NEDGE)
//   black    : [2*NSRC*NEDGE, 2*NSRC*NEDGE + NEDGE)
//   p2d1     : [HDR, HDR + 2P)
//   p2d2     : [HDR + 2P, HDR + 10P)
#define HDR (2 * NSRC * NEDGE + NEDGE) // 54000

typedef float vf4 __attribute__((ext_vector_type(4)));
typedef float vf2 __attribute__((ext_vector_type(2)));
// <2 x float> load with align(4): backend still selects global_load_dwordx2
// (gfx950 supports unaligned global access). One VMEM op per row-pair
// instead of two global_load_dword. (r5: -24us on the 4pt structure.)
typedef vf2 uvf2 __attribute__((aligned(4)));

__device__ __forceinline__ vf2 ld2(const float* __restrict__ p) {
    return *(const uvf2*)p;
}

// Kernel A: exclusive prefix sum of num_per_edge -> per-edge point offsets.
// Kept as a separate 1-block kernel: per-block fused scan cost ~25us
// aggregate VALU (r4 post-mortem, VALUBusy 37->46%).
__global__ void __launch_bounds__(256)
scan_kernel(const int* __restrict__ npe, int* __restrict__ bg) {
    __shared__ int part[256];
    int t = threadIdx.x;
    int base = t * 24;            // 256*24 = 6144 >= 6000
    int loc[24];
    int s = 0;
#pragma unroll
    for (int i = 0; i < 24; ++i) {
        int idx = base + i;
        int v = (idx < NEDGE) ? npe[idx] : 0;
        loc[i] = s;
        s += v;
    }
    part[t] = s;
    __syncthreads();
    int own = s;
    for (int off = 1; off < 256; off <<= 1) {
        int v = (t >= off) ? part[t - off] : 0;
        __syncthreads();
        part[t] += v;
        __syncthreads();
    }
    int myoff = part[t] - own;    // exclusive prefix of this thread's chunk
#pragma unroll
    for (int i = 0; i < 24; ++i) {
        int idx = base + i;
        if (idx < NEDGE) bg[idx] = myoff + loc[i];
    }
}

// Kernel B: one block per edge, 512-pt chunks, 2 points/thread.
// p2d stores: staged through LDS and re-partitioned by destination 64B line.
// All full lines are NT (no L2 write-allocate -> images stay L2-resident;
// r1 evidence: all-NT => FETCH 38MB; r5 cached-mix => 74MB). The 32B
// head/tail partials of misaligned streams (edge offsets are multiples of
// 160B => misalignment is always exactly 32B) go through cached stores so
// L2 merges them with the neighboring edge's partials (r1 evidence: NT
// partial lines double WRITE: 367MB vs 244MB ideal).
__global__ void __launch_bounds__(256)
points_kernel(const float* __restrict__ sp,
              const float* __restrict__ epnt,
              const float* __restrict__ K,
              const float* __restrict__ T,
              const int* __restrict__ npe,
              const int* __restrict__ bg,
              const float* __restrict__ imgs,
              float* __restrict__ out,
              int P) {
    const int e = blockIdx.x;
    const int nsamp = npe[e];          // num_h * 20, even, >= 40
    const int nh = nsamp / 20;
    const int b20 = bg[e];
    const int t = threadIdx.x;
    const int lane = t & 63, wid = t >> 6;

    __shared__ float DX[1000];         // num_h clipped to [2,1000]
    __shared__ float DY[20];
    __shared__ float rS[4][5];
    __shared__ int   rM[4];
    __shared__ float ldsP[NVIEW][1024]; // chunk p2d staging (5 x 4KB)

    // ---- coord tables (bit-exact vs numpy: f64 divide then f32 cast) ----
    for (int h = t; h < nh; h += 256)
        DX[h] = (float)((double)h / (double)(nh - 1));
    if (t < 20)
        DY[t] = (t < 10) ? -(float)((double)(9 - t) / 9.0)
                         :  (float)((double)(t - 10) / 9.0);

    // ---- per-edge projection params (uniform -> scalar regs) ----
    float Ax[NVIEW], Ay[NVIEW], Az[NVIEW], Aw[NVIEW], Bx[NVIEW], By[NVIEW];
    {
        float sx = sp[3 * e], sy = sp[3 * e + 1], sz = sp[3 * e + 2];
        float ex = epnt[3 * e], ey = epnt[3 * e + 1], ez = epnt[3 * e + 2];
#pragma unroll
        for (int v = 0; v < NVIEW; ++v) {
            float as, bs, cs, ae, be, ce;
            if (v == 0) {
                as = K[0] * sx + K[1] * sy + K[2] * sz;
                bs = K[3] * sx + K[4] * sy + K[5] * sz;
                cs = K[6] * sx + K[7] * sy + K[8] * sz;
                ae = K[0] * ex + K[1] * ey + K[2] * ez;
                be = K[3] * ex + K[4] * ey + K[5] * ez;
                ce = K[6] * ex + K[7] * ey + K[8] * ez;
            } else {
                const float* tt = T + (v - 1) * 12;
                as = tt[0] * sx + tt[1] * sy + tt[2] * sz + tt[3];
                bs = tt[4] * sx + tt[5] * sy + tt[6] * sz + tt[7];
                cs = tt[8] * sx + tt[9] * sy + tt[10] * sz + tt[11];
                ae = tt[0] * ex + tt[1] * ey + tt[2] * ez + tt[3];
                be = tt[4] * ex + tt[5] * ey + tt[6] * ez + tt[7];
                ce = tt[8] * ex + tt[9] * ey + tt[10] * ez + tt[11];
            }
            float u0 = as / (cs + 1e-6f);
            float w0 = bs / (cs + 1e-6f);
            float u1 = ae / (ce + 1e-6f);
            float w1 = be / (ce + 1e-6f);
            float dx = u1 - u0, dy = w1 - w0;
            float cxx = dy, cyy = -dx;   // cross([dx,dy,0],[0,0,1])
            float nrm = sqrtf(cxx * cxx + cyy * cyy);
            float inv = 1.f / (nrm + 1e-6f) * (10.0f / (float)IMG_W);
            Ax[v] = u0; Ay[v] = w0; Az[v] = dx; Aw[v] = dy;
            Bx[v] = cxx * inv; By[v] = cyy * inv;
        }
    }

    // ---- per-view store bases + head misalignment (0 or 32 bytes;
    //      chunk stride is 4096B so alignment is iteration-invariant) ----
    float* vbase[NVIEW];
    int    headB[NVIEW];
    {
        size_t gb = (size_t)b20;
        vbase[0] = out + HDR + 2 * gb;
#pragma unroll
        for (int s = 0; s < NSRC; ++s)
            vbase[s + 1] = out + HDR + 2 * (size_t)P + 2 * ((size_t)s * P + gb);
#pragma unroll
        for (int v = 0; v < NVIEW; ++v)
            headB[v] = (int)(((size_t)vbase[v]) & 63);
    }
    __syncthreads();

    float accs[NSRC] = {0.f, 0.f, 0.f, 0.f};
    float accB = 0.f;
    unsigned maskAcc = 0x1Fu;

    for (int base = 0; base < nsamp; base += 512) {
        int p0 = base + 2 * t;
        bool valid = (p0 < nsamp);     // nsamp even => p0+1 also valid
        int remPts = nsamp - base; if (remPts > 512) remPts = 512;
        const int Lb = remPts * 8;     // bytes this chunk (multiple of 16)

        float px[2 * NVIEW], py[2 * NVIEW];
        if (valid) {
            int h = p0 / 20;
            int m0 = p0 - h * 20;      // even => m0+1 < 20, same h
            float xk = DX[h];
            float y0 = DY[m0];
            float y1 = DY[m0 + 1];

            unsigned mb0 = 0, mb1 = 0;
#pragma unroll
            for (int v = 0; v < NVIEW; ++v) {
                float Sx = fmaf(Az[v], xk, Ax[v]);   // shared across the pair
                float Sy = fmaf(Aw[v], xk, Ay[v]);
                float ux0 = fmaf(Bx[v], y0, Sx);
                float uy0 = fmaf(By[v], y0, Sy);
                float ux1 = fmaf(Bx[v], y1, Sx);
                float uy1 = fmaf(By[v], y1, Sy);
                if ((ux0 > 0.f) && (ux0 < 1.f) && (uy0 > 0.f) && (uy0 < 1.f))
                    mb0 |= (1u << v);
                if ((ux1 > 0.f) && (ux1 < 1.f) && (uy1 > 0.f) && (uy1 < 1.f))
                    mb1 |= (1u << v);
                px[0 * NVIEW + v] = fminf(fmaxf(ux0, 0.f), 0.999999f);
                py[0 * NVIEW + v] = fminf(fmaxf(uy0, 0.f), 0.999999f);
                px[1 * NVIEW + v] = fminf(fmaxf(ux1, 0.f), 0.999999f);
                py[1 * NVIEW + v] = fminf(fmaxf(uy1, 0.f), 0.999999f);
            }
            maskAcc &= mb0 & mb1;
        }

        // ---- p2d store phase: LDS-stage, then line-partitioned stores ----
        __syncthreads();               // previous iteration's ldsP reads done
        if (valid) {
#pragma unroll
            for (int v = 0; v < NVIEW; ++v) {
                vf4 d;
                d.x = px[0 * NVIEW + v]; d.y = py[0 * NVIEW + v];
                d.z = px[1 * NVIEW + v]; d.w = py[1 * NVIEW + v];
                *(vf4*)&ldsP[v][4 * t] = d;
            }
        }
        __syncthreads();
#pragma unroll
        for (int v = 0; v < NVIEW; ++v) {
            char* Sb = (char*)(vbase[v] + 2 * base);
            const int head = headB[v];                 // 0 or 32
            const int tail = (head + Lb) & 63;         // 0 or 32
            const int interior = (Lb - head - tail) >> 4;
            if (t < interior) {                        // full-line NT bulk
                vf4 d = *(const vf4*)&ldsP[v][(head >> 2) + 4 * t];
                __builtin_nontemporal_store(d, (vf4*)(Sb + head + 16 * t));
            }
            if (head && t < 2) {                       // 32B head partial
                vf4 d = *(const vf4*)&ldsP[v][4 * t];
                *(vf4*)(Sb + 16 * t) = d;              // cached: L2 merges
            }
            if (tail && t >= 2 && t < 4) {             // 32B tail partial
                int off = Lb - tail + 16 * (t - 2);
                vf4 d = *(const vf4*)&ldsP[v][off >> 2];
                *(vf4*)(Sb + off) = d;                 // cached: L2 merges
            }
        }

        if (valid) {
            // issue all 20 row-pair gathers; px/py -> wx/wy in place
            vf2 r0[2 * NVIEW], r1[2 * NVIEW];
            unsigned hib = 0;
#pragma unroll
            for (int k = 0; k < 2; ++k) {
#pragma unroll
                for (int v = 0; v < NVIEW; ++v) {
                    int j = k * NVIEW + v;
                    float fx = px[j] * (float)IMG_W - 0.5f;
                    float fy = py[j] * (float)IMG_W - 0.5f;
                    float xf = floorf(fx), yf = floorf(fy);
                    px[j] = fx - xf;
                    py[j] = fy - yf;
                    int x0 = (int)xf;
                    int y0i = (int)yf;
                    int xc = min(max(x0, 0), IMG_W - 2);
                    int yc0 = min(max(y0i, 0), IMG_W - 1);
                    int yc1 = min(yc0 + 1, IMG_W - 1);
                    if (x0 >= IMG_W - 1) hib |= (1u << j);
                    const float* im = imgs + v * IMG_PIX;
                    r0[j] = ld2(im + yc0 * IMG_W + xc);
                    r1[j] = ld2(im + yc1 * IMG_W + xc);
                }
            }
            // combine + accumulate
#pragma unroll
            for (int k = 0; k < 2; ++k) {
                float sval[NVIEW];
#pragma unroll
                for (int v = 0; v < NVIEW; ++v) {
                    int j = k * NVIEW + v;
                    bool hi = (hib >> j) & 1u;
                    float v00 = hi ? r0[j].y : r0[j].x;
                    float v01 = r0[j].y;
                    float v10 = hi ? r1[j].y : r1[j].x;
                    float v11 = r1[j].y;
                    float wxv = px[j], wyv = py[j];
                    sval[v] = (v00 * (1.f - wxv) + v01 * wxv) * (1.f - wyv)
                            + (v10 * (1.f - wxv) + v11 * wxv) * wyv;
                }
                float s1 = sval[0];
                accB += (s1 < 0.01f) ? 1.f : 0.f;
#pragma unroll
                for (int s = 0; s < NSRC; ++s) {
                    float d = sval[s + 1] - s1;
                    accs[s] += d * d;
                }
            }
        }
    }

    // ---- block reduction: wave shuffles then LDS across 4 waves ----
    int mi = (int)maskAcc;
#pragma unroll
    for (int off = 32; off > 0; off >>= 1) {
        accs[0] += __shfl_down(accs[0], off);
        accs[1] += __shfl_down(accs[1], off);
        accs[2] += __shfl_down(accs[2], off);
        accs[3] += __shfl_down(accs[3], off);
        accB    += __shfl_down(accB, off);
        mi      &= __shfl_down(mi, off);
    }
    if (lane == 0) {
        rS[wid][0] = accs[0]; rS[wid][1] = accs[1];
        rS[wid][2] = accs[2]; rS[wid][3] = accs[3];
        rS[wid][4] = accB;
        rM[wid] = mi;
    }
    __syncthreads();
    if (t == 0) {
        float s0 = 0.f, s1 = 0.f, s2 = 0.f, s3 = 0.f, sB = 0.f;
        int m = 0x1F;
#pragma unroll
        for (int w = 0; w < 4; ++w) {
            s0 += rS[w][0]; s1 += rS[w][1]; s2 += rS[w][2]; s3 += rS[w][3];
            sB += rS[w][4];
            m  &= rM[w];
        }
        float cnt = (float)nsamp;
        out[0 * NEDGE + e] = s0 / cnt;
        out[1 * NEDGE + e] = s1 / cnt;
        out[2 * NEDGE + e] = s2 / cnt;
        out[3 * NEDGE + e] = s3 / cnt;
        bool vm1 = m & 1;
#pragma unroll
        for (int s = 0; s < NSRC; ++s)
            out[NSRC * NEDGE + s * NEDGE + e] =
                (vm1 && ((m >> (s + 1)) & 1)) ? 1.f : 0.f;
        out[2 * NSRC * NEDGE + e] = ((sB / cnt) > 0.5f) ? 1.f : 0.f;
    }
}

extern "C" void kernel_launch(void* const* d_in, const int* in_sizes, int n_in,
                              void* d_out, int out_size, void* d_ws, size_t ws_size,
                              hipStream_t stream) {
    const float* start = (const float*)d_in[0];
    const float* endp  = (const float*)d_in[1];
    const float* imgs  = (const float*)d_in[2];
    const float* trans = (const float*)d_in[3];
    const float* K     = (const float*)d_in[4];
    const int*   npe   = (const int*)d_in[8];
    int P = in_sizes[5];

    int* bg = (int*)d_ws;              // 24000 B

    float* out = (float*)d_out;
    scan_kernel<<<1, 256, 0, stream>>>(npe, bg);
    points_kernel<<<NEDGE, 256, 0, stream>>>(start, endp, K, trans, npe, bg,
                                             imgs, out, P);
}

// Round 8
// 378.703 us; speedup vs baseline: 1.0239x; 1.0239x over previous
//
#include <hip/hip_runtime.h>
#include <math.h>

#define IMG_W   800
#define IMG_PIX (IMG_W * IMG_W)
#define NEDGE   6000
#define NSRC    4
#define NVIEW   5
// d_out layout (floats):
//   sim loss : [0, NSRC*NEDGE)
//   mask     : [NSRC*NEDGE, 2*NSRC*NEDGE)
//   black    : [2*NSRC*NEDGE, 2*NSRC*NEDGE + NEDGE)
//   p2d1     : [HDR, HDR + 2P)
//   p2d2     : [HDR + 2P, HDR + 10P)
#define HDR (2 * NSRC * NEDGE + NEDGE) // 54000

typedef float vf4 __attribute__((ext_vector_type(4)));
typedef float vf2 __attribute__((ext_vector_type(2)));
// <2 x float> load with align(4): backend selects global_load_dwordx2
// (gfx950 supports unaligned global access). One VMEM op per row-pair.
typedef vf2 uvf2 __attribute__((aligned(4)));

__device__ __forceinline__ vf2 ld2(const float* __restrict__ p) {
    return *(const uvf2*)p;
}
// 16B store; nt (wave-uniform) selects non-temporal vs cached.
// Misaligned (32B-offset) streams use cached stores so L2 merges partial
// lines (r1: all-NT 367MB vs 235MB ideal; r5/r6: 235MB = floor).
// r7 lesson: do NOT LDS-stage stores — per-chunk barriers serialize the
// latency-critical gathers and cost more than the FETCH gain.
__device__ __forceinline__ void st4(float* p, float a, float b, float c, float d,
                                    bool nt) {
    vf4 v; v.x = a; v.y = b; v.z = c; v.w = d;
    if (nt) __builtin_nontemporal_store(v, (vf4*)p);
    else    *(vf4*)p = v;
}

// Kernel A: exclusive prefix sum of num_per_edge -> per-edge point offsets.
// Separate 1-block kernel (r4: fusing per-block costs ~25us aggregate VALU).
__global__ void __launch_bounds__(256)
scan_kernel(const int* __restrict__ npe, int* __restrict__ bg) {
    __shared__ int part[256];
    int t = threadIdx.x;
    int base = t * 24;            // 256*24 = 6144 >= 6000
    int loc[24];
    int s = 0;
#pragma unroll
    for (int i = 0; i < 24; ++i) {
        int idx = base + i;
        int v = (idx < NEDGE) ? npe[idx] : 0;
        loc[i] = s;
        s += v;
    }
    part[t] = s;
    __syncthreads();
    int own = s;
    for (int off = 1; off < 256; off <<= 1) {
        int v = (t >= off) ? part[t - off] : 0;
        __syncthreads();
        part[t] += v;
        __syncthreads();
    }
    int myoff = part[t] - own;    // exclusive prefix of this thread's chunk
#pragma unroll
    for (int i = 0; i < 24; ++i) {
        int idx = base + i;
        if (idx < NEDGE) bg[idx] = myoff + loc[i];
    }
}

// Kernel B: one block per edge, 512-pt chunks, 2 points/thread (r6 structure,
// best measured). This round: lerp-form bilinear, row-delta addressing,
// gathers issued before p2d stores (wx/wy in separate regs).
__global__ void __launch_bounds__(256)
points_kernel(const float* __restrict__ sp,
              const float* __restrict__ epnt,
              const float* __restrict__ K,
              const float* __restrict__ T,
              const int* __restrict__ npe,
              const int* __restrict__ bg,
              const float* __restrict__ imgs,
              float* __restrict__ out,
              int P) {
    const int e = blockIdx.x;
    const int nsamp = npe[e];          // num_h * 20, even, >= 40
    const int nh = nsamp / 20;
    const int b20 = bg[e];
    const int t = threadIdx.x;
    const int lane = t & 63, wid = t >> 6;

    __shared__ float DX[1000];         // num_h clipped to [2,1000]
    __shared__ float DY[20];
    __shared__ float rS[4][5];
    __shared__ int   rM[4];

    // ---- coord tables (bit-exact vs numpy: f64 divide then f32 cast) ----
    for (int h = t; h < nh; h += 256)
        DX[h] = (float)((double)h / (double)(nh - 1));
    if (t < 20)
        DY[t] = (t < 10) ? -(float)((double)(9 - t) / 9.0)
                         :  (float)((double)(t - 10) / 9.0);

    // ---- per-edge projection params (uniform -> scalar regs) ----
    float Ax[NVIEW], Ay[NVIEW], Az[NVIEW], Aw[NVIEW], Bx[NVIEW], By[NVIEW];
    {
        float sx = sp[3 * e], sy = sp[3 * e + 1], sz = sp[3 * e + 2];
        float ex = epnt[3 * e], ey = epnt[3 * e + 1], ez = epnt[3 * e + 2];
#pragma unroll
        for (int v = 0; v < NVIEW; ++v) {
            float as, bs, cs, ae, be, ce;
            if (v == 0) {
                as = K[0] * sx + K[1] * sy + K[2] * sz;
                bs = K[3] * sx + K[4] * sy + K[5] * sz;
                cs = K[6] * sx + K[7] * sy + K[8] * sz;
                ae = K[0] * ex + K[1] * ey + K[2] * ez;
                be = K[3] * ex + K[4] * ey + K[5] * ez;
                ce = K[6] * ex + K[7] * ey + K[8] * ez;
            } else {
                const float* tt = T + (v - 1) * 12;
                as = tt[0] * sx + tt[1] * sy + tt[2] * sz + tt[3];
                bs = tt[4] * sx + tt[5] * sy + tt[6] * sz + tt[7];
                cs = tt[8] * sx + tt[9] * sy + tt[10] * sz + tt[11];
                ae = tt[0] * ex + tt[1] * ey + tt[2] * ez + tt[3];
                be = tt[4] * ex + tt[5] * ey + tt[6] * ez + tt[7];
                ce = tt[8] * ex + tt[9] * ey + tt[10] * ez + tt[11];
            }
            float u0 = as / (cs + 1e-6f);
            float w0 = bs / (cs + 1e-6f);
            float u1 = ae / (ce + 1e-6f);
            float w1 = be / (ce + 1e-6f);
            float dx = u1 - u0, dy = w1 - w0;
            float cxx = dy, cyy = -dx;   // cross([dx,dy,0],[0,0,1])
            float nrm = sqrtf(cxx * cxx + cyy * cyy);
            float inv = 1.f / (nrm + 1e-6f) * (10.0f / (float)IMG_W);
            Ax[v] = u0; Ay[v] = w0; Az[v] = dx; Aw[v] = dy;
            Bx[v] = cxx * inv; By[v] = cyy * inv;
        }
    }

    // ---- per-view store bases + 64B-alignment flags ----
    float* vbase[NVIEW];
    bool   val64[NVIEW];
    {
        size_t gb = (size_t)b20;
        vbase[0] = out + HDR + 2 * gb;
#pragma unroll
        for (int s = 0; s < NSRC; ++s)
            vbase[s + 1] = out + HDR + 2 * (size_t)P + 2 * ((size_t)s * P + gb);
#pragma unroll
        for (int v = 0; v < NVIEW; ++v)
            val64[v] = ((((size_t)vbase[v]) & 63) == 0);
    }
    __syncthreads();

    float accs[NSRC] = {0.f, 0.f, 0.f, 0.f};
    float accB = 0.f;
    unsigned maskAcc = 0x1Fu;

    for (int base = 0; base < nsamp; base += 512) {
        int p0 = base + 2 * t;
        bool valid = (p0 < nsamp);     // nsamp even => p0+1 also valid

        if (valid) {
            int h = p0 / 20;
            int m0 = p0 - h * 20;      // even => m0+1 < 20, same h
            float xk = DX[h];
            float y0 = DY[m0];
            float y1 = DY[m0 + 1];

            float px[2 * NVIEW], py[2 * NVIEW];
            unsigned mb0 = 0, mb1 = 0;
#pragma unroll
            for (int v = 0; v < NVIEW; ++v) {
                float Sx = fmaf(Az[v], xk, Ax[v]);   // shared across the pair
                float Sy = fmaf(Aw[v], xk, Ay[v]);
                float ux0 = fmaf(Bx[v], y0, Sx);
                float uy0 = fmaf(By[v], y0, Sy);
                float ux1 = fmaf(Bx[v], y1, Sx);
                float uy1 = fmaf(By[v], y1, Sy);
                if ((ux0 > 0.f) && (ux0 < 1.f) && (uy0 > 0.f) && (uy0 < 1.f))
                    mb0 |= (1u << v);
                if ((ux1 > 0.f) && (ux1 < 1.f) && (uy1 > 0.f) && (uy1 < 1.f))
                    mb1 |= (1u << v);
                px[0 * NVIEW + v] = fminf(fmaxf(ux0, 0.f), 0.999999f);
                py[0 * NVIEW + v] = fminf(fmaxf(uy0, 0.f), 0.999999f);
                px[1 * NVIEW + v] = fminf(fmaxf(ux1, 0.f), 0.999999f);
                py[1 * NVIEW + v] = fminf(fmaxf(uy1, 0.f), 0.999999f);
            }
            maskAcc &= mb0 & mb1;

            // ---- issue all 20 row-pair gathers FIRST (long latency);
            //      wx/wy to separate regs so px/py stay live for stores ----
            vf2 r0[2 * NVIEW], r1[2 * NVIEW];
            float wx[2 * NVIEW], wy[2 * NVIEW];
            unsigned hib = 0;
#pragma unroll
            for (int k = 0; k < 2; ++k) {
#pragma unroll
                for (int v = 0; v < NVIEW; ++v) {
                    int j = k * NVIEW + v;
                    float fx = fmaf(px[j], (float)IMG_W, -0.5f);
                    float fy = fmaf(py[j], (float)IMG_W, -0.5f);
                    float xf = floorf(fx), yf = floorf(fy);
                    wx[j] = fx - xf;
                    wy[j] = fy - yf;
                    int x0 = (int)xf;                 // in [-1, 799]
                    int y0i = (int)yf;
                    int xc = min(max(x0, 0), IMG_W - 2);
                    int yc0 = min(max(y0i, 0), IMG_W - 1);
                    int off0 = yc0 * IMG_W + xc;
                    int rowd = (yc0 < IMG_W - 1) ? IMG_W : 0; // row-delta
                    if (x0 >= IMG_W - 1) hib |= (1u << j);
                    const float* im = imgs + v * IMG_PIX;
                    r0[j] = ld2(im + off0);
                    r1[j] = ld2(im + off0 + rowd);
                }
            }

            // ---- p2d stores overlap gather latency ----
#pragma unroll
            for (int v = 0; v < NVIEW; ++v)
                st4(vbase[v] + 2 * base + 4 * t,
                    px[0 * NVIEW + v], py[0 * NVIEW + v],
                    px[1 * NVIEW + v], py[1 * NVIEW + v], val64[v]);

            // ---- combine (lerp form) + accumulate ----
#pragma unroll
            for (int k = 0; k < 2; ++k) {
                float sval[NVIEW];
#pragma unroll
                for (int v = 0; v < NVIEW; ++v) {
                    int j = k * NVIEW + v;
                    bool hi = (hib >> j) & 1u;
                    float v00 = hi ? r0[j].y : r0[j].x;
                    float v01 = r0[j].y;
                    float v10 = hi ? r1[j].y : r1[j].x;
                    float v11 = r1[j].y;
                    float top = fmaf(wx[j], v01 - v00, v00);
                    float bot = fmaf(wx[j], v11 - v10, v10);
                    sval[v] = fmaf(wy[j], bot - top, top);
                }
                float s1 = sval[0];
                accB += (s1 < 0.01f) ? 1.f : 0.f;
#pragma unroll
                for (int s = 0; s < NSRC; ++s) {
                    float d = sval[s + 1] - s1;
                    accs[s] = fmaf(d, d, accs[s]);
                }
            }
        }
    }

    // ---- block reduction: wave shuffles then LDS across 4 waves ----
    int mi = (int)maskAcc;
#pragma unroll
    for (int off = 32; off > 0; off >>= 1) {
        accs[0] += __shfl_down(accs[0], off);
        accs[1] += __shfl_down(accs[1], off);
        accs[2] += __shfl_down(accs[2], off);
        accs[3] += __shfl_down(accs[3], off);
        accB    += __shfl_down(accB, off);
        mi      &= __shfl_down(mi, off);
    }
    if (lane == 0) {
        rS[wid][0] = accs[0]; rS[wid][1] = accs[1];
        rS[wid][2] = accs[2]; rS[wid][3] = accs[3];
        rS[wid][4] = accB;
        rM[wid] = mi;
    }
    __syncthreads();
    if (t == 0) {
        float s0 = 0.f, s1 = 0.f, s2 = 0.f, s3 = 0.f, sB = 0.f;
        int m = 0x1F;
#pragma unroll
        for (int w = 0; w < 4; ++w) {
            s0 += rS[w][0]; s1 += rS[w][1]; s2 += rS[w][2]; s3 += rS[w][3];
            sB += rS[w][4];
            m  &= rM[w];
        }
        float cnt = (float)nsamp;
        out[0 * NEDGE + e] = s0 / cnt;
        out[1 * NEDGE + e] = s1 / cnt;
        out[2 * NEDGE + e] = s2 / cnt;
        out[3 * NEDGE + e] = s3 / cnt;
        bool vm1 = m & 1;
#pragma unroll
        for (int s = 0; s < NSRC; ++s)
            out[NSRC * NEDGE + s * NEDGE + e] =
                (vm1 && ((m >> (s + 1)) & 1)) ? 1.f : 0.f;
        out[2 * NSRC * NEDGE + e] = ((sB / cnt) > 0.5f) ? 1.f : 0.f;
    }
}

extern "C" void kernel_launch(void* const* d_in, const int* in_sizes, int n_in,
                              void* d_out, int out_size, void* d_ws, size_t ws_size,
                              hipStream_t stream) {
    const float* start = (const float*)d_in[0];
    const float* endp  = (const float*)d_in[1];
    const float* imgs  = (const float*)d_in[2];
    const float* trans = (const float*)d_in[3];
    const float* K     = (const float*)d_in[4];
    const int*   npe   = (const int*)d_in[8];
    int P = in_sizes[5];

    int* bg = (int*)d_ws;              // 24000 B

    float* out = (float*)d_out;
    scan_kernel<<<1, 256, 0, stream>>>(npe, bg);
    points_kernel<<<NEDGE, 256, 0, stream>>>(start, endp, K, trans, npe, bg,
                                             imgs, out, P);
}

// Round 9
// 364.117 us; speedup vs baseline: 1.0649x; 1.0401x over previous
//
#include <hip/hip_runtime.h>
#include <math.h>

#define IMG_W   800
#define IMG_PIX (IMG_W * IMG_W)
#define NEDGE   6000
#define NSRC    4
#define NVIEW   5
// d_out layout (floats):
//   sim loss : [0, NSRC*NEDGE)
//   mask     : [NSRC*NEDGE, 2*NSRC*NEDGE)
//   black    : [2*NSRC*NEDGE, 2*NSRC*NEDGE + NEDGE)
//   p2d1     : [HDR, HDR + 2P)
//   p2d2     : [HDR + 2P, HDR + 10P)
#define HDR (2 * NSRC * NEDGE + NEDGE) // 54000

typedef float vf4 __attribute__((ext_vector_type(4)));
typedef float vf2 __attribute__((ext_vector_type(2)));
// <2 x float> load with align(4): backend selects global_load_dwordx2
// (gfx950 supports unaligned global access). One VMEM op per row-pair.
typedef vf2 uvf2 __attribute__((aligned(4)));

__device__ __forceinline__ vf2 ld2(const float* __restrict__ p) {
    return *(const uvf2*)p;
}
// All p2d stores are non-temporal. Rationale (r8 post-mortem): the lane-
// contiguous wave store coalesces into full 64B lines (only 32B head/tail
// partial when the stream is 32B-misaligned, ~6% amplification). r1's
// measured 1.55x NT amplification came from its holey 32B-stride layout
// and does not apply here. Cached fallback for misaligned streams (r5-r8)
// allocated ~118MB/launch in L2 and evicted the image working set
// (FETCH 38MB -> 74MB).
__device__ __forceinline__ void st4nt(float* p, float a, float b, float c,
                                      float d) {
    vf4 v; v.x = a; v.y = b; v.z = c; v.w = d;
    __builtin_nontemporal_store(v, (vf4*)p);
}

// Kernel A: exclusive prefix sum of num_per_edge -> per-edge point offsets.
// Separate 1-block kernel (r4: fusing per-block costs ~25us aggregate VALU).
__global__ void __launch_bounds__(256)
scan_kernel(const int* __restrict__ npe, int* __restrict__ bg) {
    __shared__ int part[256];
    int t = threadIdx.x;
    int base = t * 24;            // 256*24 = 6144 >= 6000
    int loc[24];
    int s = 0;
#pragma unroll
    for (int i = 0; i < 24; ++i) {
        int idx = base + i;
        int v = (idx < NEDGE) ? npe[idx] : 0;
        loc[i] = s;
        s += v;
    }
    part[t] = s;
    __syncthreads();
    int own = s;
    for (int off = 1; off < 256; off <<= 1) {
        int v = (t >= off) ? part[t - off] : 0;
        __syncthreads();
        part[t] += v;
        __syncthreads();
    }
    int myoff = part[t] - own;    // exclusive prefix of this thread's chunk
#pragma unroll
    for (int i = 0; i < 24; ++i) {
        int idx = base + i;
        if (idx < NEDGE) bg[idx] = myoff + loc[i];
    }
}

// Kernel B: one block per edge, 512-pt chunks, 2 points/thread (r6 structure).
// Lerp-form bilinear, row-delta addressing, gathers issued before p2d stores.
__global__ void __launch_bounds__(256)
points_kernel(const float* __restrict__ sp,
              const float* __restrict__ epnt,
              const float* __restrict__ K,
              const float* __restrict__ T,
              const int* __restrict__ npe,
              const int* __restrict__ bg,
              const float* __restrict__ imgs,
              float* __restrict__ out,
              int P) {
    const int e = blockIdx.x;
    const int nsamp = npe[e];          // num_h * 20, even, >= 40
    const int nh = nsamp / 20;
    const int b20 = bg[e];
    const int t = threadIdx.x;
    const int lane = t & 63, wid = t >> 6;

    __shared__ float DX[1000];         // num_h clipped to [2,1000]
    __shared__ float DY[20];
    __shared__ float rS[4][5];
    __shared__ int   rM[4];

    // ---- coord tables (bit-exact vs numpy: f64 divide then f32 cast) ----
    for (int h = t; h < nh; h += 256)
        DX[h] = (float)((double)h / (double)(nh - 1));
    if (t < 20)
        DY[t] = (t < 10) ? -(float)((double)(9 - t) / 9.0)
                         :  (float)((double)(t - 10) / 9.0);

    // ---- per-edge projection params (uniform -> scalar regs) ----
    float Ax[NVIEW], Ay[NVIEW], Az[NVIEW], Aw[NVIEW], Bx[NVIEW], By[NVIEW];
    {
        float sx = sp[3 * e], sy = sp[3 * e + 1], sz = sp[3 * e + 2];
        float ex = epnt[3 * e], ey = epnt[3 * e + 1], ez = epnt[3 * e + 2];
#pragma unroll
        for (int v = 0; v < NVIEW; ++v) {
            float as, bs, cs, ae, be, ce;
            if (v == 0) {
                as = K[0] * sx + K[1] * sy + K[2] * sz;
                bs = K[3] * sx + K[4] * sy + K[5] * sz;
                cs = K[6] * sx + K[7] * sy + K[8] * sz;
                ae = K[0] * ex + K[1] * ey + K[2] * ez;
                be = K[3] * ex + K[4] * ey + K[5] * ez;
                ce = K[6] * ex + K[7] * ey + K[8] * ez;
            } else {
                const float* tt = T + (v - 1) * 12;
                as = tt[0] * sx + tt[1] * sy + tt[2] * sz + tt[3];
                bs = tt[4] * sx + tt[5] * sy + tt[6] * sz + tt[7];
                cs = tt[8] * sx + tt[9] * sy + tt[10] * sz + tt[11];
                ae = tt[0] * ex + tt[1] * ey + tt[2] * ez + tt[3];
                be = tt[4] * ex + tt[5] * ey + tt[6] * ez + tt[7];
                ce = tt[8] * ex + tt[9] * ey + tt[10] * ez + tt[11];
            }
            float u0 = as / (cs + 1e-6f);
            float w0 = bs / (cs + 1e-6f);
            float u1 = ae / (ce + 1e-6f);
            float w1 = be / (ce + 1e-6f);
            float dx = u1 - u0, dy = w1 - w0;
            float cxx = dy, cyy = -dx;   // cross([dx,dy,0],[0,0,1])
            float nrm = sqrtf(cxx * cxx + cyy * cyy);
            float inv = 1.f / (nrm + 1e-6f) * (10.0f / (float)IMG_W);
            Ax[v] = u0; Ay[v] = w0; Az[v] = dx; Aw[v] = dy;
            Bx[v] = cxx * inv; By[v] = cyy * inv;
        }
    }

    // ---- per-view store bases ----
    float* vbase[NVIEW];
    {
        size_t gb = (size_t)b20;
        vbase[0] = out + HDR + 2 * gb;
#pragma unroll
        for (int s = 0; s < NSRC; ++s)
            vbase[s + 1] = out + HDR + 2 * (size_t)P + 2 * ((size_t)s * P + gb);
    }
    __syncthreads();

    float accs[NSRC] = {0.f, 0.f, 0.f, 0.f};
    float accB = 0.f;
    unsigned maskAcc = 0x1Fu;

    for (int base = 0; base < nsamp; base += 512) {
        int p0 = base + 2 * t;
        bool valid = (p0 < nsamp);     // nsamp even => p0+1 also valid

        if (valid) {
            int h = p0 / 20;
            int m0 = p0 - h * 20;      // even => m0+1 < 20, same h
            float xk = DX[h];
            float y0 = DY[m0];
            float y1 = DY[m0 + 1];

            float px[2 * NVIEW], py[2 * NVIEW];
            unsigned mb0 = 0, mb1 = 0;
#pragma unroll
            for (int v = 0; v < NVIEW; ++v) {
                float Sx = fmaf(Az[v], xk, Ax[v]);   // shared across the pair
                float Sy = fmaf(Aw[v], xk, Ay[v]);
                float ux0 = fmaf(Bx[v], y0, Sx);
                float uy0 = fmaf(By[v], y0, Sy);
                float ux1 = fmaf(Bx[v], y1, Sx);
                float uy1 = fmaf(By[v], y1, Sy);
                if ((ux0 > 0.f) && (ux0 < 1.f) && (uy0 > 0.f) && (uy0 < 1.f))
                    mb0 |= (1u << v);
                if ((ux1 > 0.f) && (ux1 < 1.f) && (uy1 > 0.f) && (uy1 < 1.f))
                    mb1 |= (1u << v);
                px[0 * NVIEW + v] = fminf(fmaxf(ux0, 0.f), 0.999999f);
                py[0 * NVIEW + v] = fminf(fmaxf(uy0, 0.f), 0.999999f);
                px[1 * NVIEW + v] = fminf(fmaxf(ux1, 0.f), 0.999999f);
                py[1 * NVIEW + v] = fminf(fmaxf(uy1, 0.f), 0.999999f);
            }
            maskAcc &= mb0 & mb1;

            // ---- issue all 20 row-pair gathers FIRST (long latency);
            //      wx/wy to separate regs so px/py stay live for stores ----
            vf2 r0[2 * NVIEW], r1[2 * NVIEW];
            float wx[2 * NVIEW], wy[2 * NVIEW];
            unsigned hib = 0;
#pragma unroll
            for (int k = 0; k < 2; ++k) {
#pragma unroll
                for (int v = 0; v < NVIEW; ++v) {
                    int j = k * NVIEW + v;
                    float fx = fmaf(px[j], (float)IMG_W, -0.5f);
                    float fy = fmaf(py[j], (float)IMG_W, -0.5f);
                    float xf = floorf(fx), yf = floorf(fy);
                    wx[j] = fx - xf;
                    wy[j] = fy - yf;
                    int x0 = (int)xf;                 // in [-1, 799]
                    int y0i = (int)yf;
                    int xc = min(max(x0, 0), IMG_W - 2);
                    int yc0 = min(max(y0i, 0), IMG_W - 1);
                    int off0 = yc0 * IMG_W + xc;
                    int rowd = (yc0 < IMG_W - 1) ? IMG_W : 0; // row-delta
                    if (x0 >= IMG_W - 1) hib |= (1u << j);
                    const float* im = imgs + v * IMG_PIX;
                    r0[j] = ld2(im + off0);
                    r1[j] = ld2(im + off0 + rowd);
                }
            }

            // ---- p2d stores overlap gather latency ----
#pragma unroll
            for (int v = 0; v < NVIEW; ++v)
                st4nt(vbase[v] + 2 * base + 4 * t,
                      px[0 * NVIEW + v], py[0 * NVIEW + v],
                      px[1 * NVIEW + v], py[1 * NVIEW + v]);

            // ---- combine (lerp form) + accumulate ----
#pragma unroll
            for (int k = 0; k < 2; ++k) {
                float sval[NVIEW];
#pragma unroll
                for (int v = 0; v < NVIEW; ++v) {
                    int j = k * NVIEW + v;
                    bool hi = (hib >> j) & 1u;
                    float v00 = hi ? r0[j].y : r0[j].x;
                    float v01 = r0[j].y;
                    float v10 = hi ? r1[j].y : r1[j].x;
                    float v11 = r1[j].y;
                    float top = fmaf(wx[j], v01 - v00, v00);
                    float bot = fmaf(wx[j], v11 - v10, v10);
                    sval[v] = fmaf(wy[j], bot - top, top);
                }
                float s1 = sval[0];
                accB += (s1 < 0.01f) ? 1.f : 0.f;
#pragma unroll
                for (int s = 0; s < NSRC; ++s) {
                    float d = sval[s + 1] - s1;
                    accs[s] = fmaf(d, d, accs[s]);
                }
            }
        }
    }

    // ---- block reduction: wave shuffles then LDS across 4 waves ----
    int mi = (int)maskAcc;
#pragma unroll
    for (int off = 32; off > 0; off >>= 1) {
        accs[0] += __shfl_down(accs[0], off);
        accs[1] += __shfl_down(accs[1], off);
        accs[2] += __shfl_down(accs[2], off);
        accs[3] += __shfl_down(accs[3], off);
        accB    += __shfl_down(accB, off);
        mi      &= __shfl_down(mi, off);
    }
    if (lane == 0) {
        rS[wid][0] = accs[0]; rS[wid][1] = accs[1];
        rS[wid][2] = accs[2]; rS[wid][3] = accs[3];
        rS[wid][4] = accB;
        rM[wid] = mi;
    }
    __syncthreads();
    if (t == 0) {
        float s0 = 0.f, s1 = 0.f, s2 = 0.f, s3 = 0.f, sB = 0.f;
        int m = 0x1F;
#pragma unroll
        for (int w = 0; w < 4; ++w) {
            s0 += rS[w][0]; s1 += rS[w][1]; s2 += rS[w][2]; s3 += rS[w][3];
            sB += rS[w][4];
            m  &= rM[w];
        }
        float cnt = (float)nsamp;
        out[0 * NEDGE + e] = s0 / cnt;
        out[1 * NEDGE + e] = s1 / cnt;
        out[2 * NEDGE + e] = s2 / cnt;
        out[3 * NEDGE + e] = s3 / cnt;
        bool vm1 = m & 1;
#pragma unroll
        for (int s = 0; s < NSRC; ++s)
            out[NSRC * NEDGE + s * NEDGE + e] =
                (vm1 && ((m >> (s + 1)) & 1)) ? 1.f : 0.f;
        out[2 * NSRC * NEDGE + e] = ((sB / cnt) > 0.5f) ? 1.f : 0.f;
    }
}

extern "C" void kernel_launch(void* const* d_in, const int* in_sizes, int n_in,
                              void* d_out, int out_size, void* d_ws, size_t ws_size,
                              hipStream_t stream) {
    const float* start = (const float*)d_in[0];
    const float* endp  = (const float*)d_in[1];
    const float* imgs  = (const float*)d_in[2];
    const float* trans = (const float*)d_in[3];
    const float* K     = (const float*)d_in[4];
    const int*   npe   = (const int*)d_in[8];
    int P = in_sizes[5];

    int* bg = (int*)d_ws;              // 24000 B

    float* out = (float*)d_out;
    scan_kernel<<<1, 256, 0, stream>>>(npe, bg);
    points_kernel<<<NEDGE, 256, 0, stream>>>(start, endp, K, trans, npe, bg,
                                             imgs, out, P);
}